// Round 1
// baseline (168.485 us; speedup 1.0000x reference)
//
#include <hip/hip_runtime.h>

#define BATCH 32
#define HDIM 224
#define WDIM 224
#define CDIM 3
#define KTOT (HDIM * WDIM * CDIM)   // 150528
#define HID 64
#define KCHUNK 384
#define NBLK1 (KTOT / KCHUNK)       // 392
#define PIX (HDIM * WDIM)           // 50176
#define BLK3 (PIX / 256)            // 196

// ---------------- Kernel 1: h_acc = flat @ w1 (split-K, atomic reduce) -------
__global__ __launch_bounds__(256) void k1_gemm(const float* __restrict__ flat,
                                               const float* __restrict__ w1,
                                               float* __restrict__ hacc) {
    const int tid  = threadIdx.x;
    const int hid  = tid & 63;      // 0..63, coalesced over w1 row
    const int bg   = tid >> 6;      // 0..3 (wave id)
    const int bbase = bg * 8;       // this wave covers 8 batches

    float acc[8];
#pragma unroll
    for (int j = 0; j < 8; ++j) acc[j] = 0.0f;

    const int k0 = blockIdx.x * KCHUNK;
    for (int kk = 0; kk < KCHUNK; kk += 4) {
        const int k = k0 + kk;
        float4 x4[8];
#pragma unroll
        for (int j = 0; j < 8; ++j)
            x4[j] = *(const float4*)(flat + (size_t)(bbase + j) * KTOT + k);
#pragma unroll
        for (int i = 0; i < 4; ++i) {
            const float w = w1[(size_t)(k + i) * HID + hid];
#pragma unroll
            for (int j = 0; j < 8; ++j) {
                const float xv = ((const float*)&x4[j])[i];
                acc[j] = fmaf(xv, w, acc[j]);
            }
        }
    }
#pragma unroll
    for (int j = 0; j < 8; ++j)
        atomicAdd(hacc + (bbase + j) * HID + hid, acc[j]);
}

// ---------------- Kernel 2: h = tanh(acc + b1); theta = tanh(h @ w2 + b2) ----
__global__ __launch_bounds__(256) void k2_head(const float* __restrict__ hacc,
                                               const float* __restrict__ b1,
                                               const float* __restrict__ w2,
                                               const float* __restrict__ b2,
                                               float* __restrict__ theta) {
    __shared__ float h[BATCH * HID];
    const int tid = threadIdx.x;
    for (int idx = tid; idx < BATCH * HID; idx += 256)
        h[idx] = tanhf(hacc[idx] + b1[idx & (HID - 1)]);
    __syncthreads();
    if (tid < BATCH * 6) {
        const int b = tid / 6;
        const int j = tid - b * 6;
        float s = b2[j];
#pragma unroll
        for (int t = 0; t < HID; ++t)
            s = fmaf(h[b * HID + t], w2[t * 6 + j], s);
        theta[tid] = tanhf(s);
    }
}

// ---------------- Kernel 3: affine grid + bilinear sampling ------------------
__global__ __launch_bounds__(256) void k3_sample(const float* __restrict__ img,
                                                 const float* __restrict__ theta,
                                                 float* __restrict__ out) {
    const int b   = blockIdx.x / BLK3;
    const int pix = (blockIdx.x - b * BLK3) * 256 + threadIdx.x;
    const int i   = pix / WDIM;          // row (y)
    const int j   = pix - i * WDIM;      // col (x)

    const float* th = theta + b * 6;
    const float t0 = th[0], t1 = th[1], t2 = th[2];
    const float t3 = th[3], t4 = th[4], t5 = th[5];

    const float xt = (2.0f * (float)j - (float)(WDIM - 1)) / (float)(WDIM - 1);
    const float yt = (2.0f * (float)i - (float)(HDIM - 1)) / (float)(HDIM - 1);

    const float xs = t0 * xt + t1 * yt + t2;
    const float ys = t3 * xt + t4 * yt + t5;

    const float x = 0.5f * (xs + 1.0f) * (float)(WDIM - 1);
    const float y = 0.5f * (ys + 1.0f) * (float)(HDIM - 1);

    const int x0 = (int)floorf(x);
    const int y0 = (int)floorf(y);
    const int x1 = x0 + 1;
    const int y1 = y0 + 1;

    const int x0c = min(max(x0, 0), WDIM - 1);
    const int x1c = min(max(x1, 0), WDIM - 1);
    const int y0c = min(max(y0, 0), HDIM - 1);
    const int y1c = min(max(y1, 0), HDIM - 1);

    // Reference computes weights from the CLIPPED corner coordinates.
    const float x0f = (float)x0c, x1f = (float)x1c;
    const float y0f = (float)y0c, y1f = (float)y1c;

    const float wa = (x1f - x) * (y1f - y);
    const float wb = (x1f - x) * (y - y0f);
    const float wc = (x - x0f) * (y1f - y);
    const float wd = (x - x0f) * (y - y0f);

    const float* base = img + (size_t)b * KTOT;
    const float* pa = base + (size_t)(y0c * WDIM + x0c) * 3;
    const float* pb = base + (size_t)(y1c * WDIM + x0c) * 3;
    const float* pc = base + (size_t)(y0c * WDIM + x1c) * 3;
    const float* pd = base + (size_t)(y1c * WDIM + x1c) * 3;

    float* po = out + (size_t)b * KTOT + (size_t)pix * 3;
#pragma unroll
    for (int c = 0; c < 3; ++c)
        po[c] = wa * pa[c] + wb * pb[c] + wc * pc[c] + wd * pd[c];
}

extern "C" void kernel_launch(void* const* d_in, const int* in_sizes, int n_in,
                              void* d_out, int out_size, void* d_ws, size_t ws_size,
                              hipStream_t stream) {
    const float* inputs = (const float*)d_in[0];
    const float* w1     = (const float*)d_in[1];
    const float* b1     = (const float*)d_in[2];
    const float* w2     = (const float*)d_in[3];
    const float* b2     = (const float*)d_in[4];
    float* out = (float*)d_out;

    float* hacc  = (float*)d_ws;               // 32*64 floats
    float* theta = hacc + BATCH * HID;         // 32*6 floats

    hipMemsetAsync(hacc, 0, BATCH * HID * sizeof(float), stream);
    k1_gemm<<<NBLK1, 256, 0, stream>>>(inputs, w1, hacc);
    k2_head<<<1, 256, 0, stream>>>(hacc, b1, w2, b2, theta);
    k3_sample<<<BATCH * BLK3, 256, 0, stream>>>(inputs, theta, out);
}

// Round 2
// 141.996 us; speedup vs baseline: 1.1865x; 1.1865x over previous
//
#include <hip/hip_runtime.h>

#define BATCH 32
#define HDIM 224
#define WDIM 224
#define CDIM 3
#define KTOT (HDIM * WDIM * CDIM)   // 150528
#define HID 64
#define KCHUNK 128
#define NBLK1 (KTOT / KCHUNK)       // 1176
#define PIX (HDIM * WDIM)           // 50176
#define BLK3 (PIX / 256)            // 196

// ---------------- Kernel 1: hacc = flat @ w1 (split-K, LDS-staged) ----------
// Block: 256 thr = 4 waves. Block owns k-range [k0, k0+128).
// Wave w owns [k0+32w, k0+32w+32). Thread lane = hid, holds acc for all 32 b.
__global__ __launch_bounds__(256, 5) void k1_gemm(const float* __restrict__ flat,
                                                  const float* __restrict__ w1,
                                                  float* __restrict__ hacc) {
    __shared__ float smem[8192];                 // 32 KB, dual-purpose
    const int tid  = threadIdx.x;
    const int lane = tid & 63;                   // hid
    const int wave = tid >> 6;
    const int k0   = blockIdx.x * KCHUNK;

    // --- Stage flat[32][k0..k0+128) into LDS (16 KB), coalesced float4 ---
#pragma unroll
    for (int t = 0; t < 4; ++t) {
        const int idx = tid + t * 256;           // 0..1023
        const int b   = idx >> 5;                // 0..31
        const int kq  = idx & 31;                // 0..31 (float4 index)
        const float4 v = *(const float4*)(flat + (size_t)b * KTOT + k0 + kq * 4);
        *(float4*)(smem + b * 128 + kq * 4) = v;
    }
    __syncthreads();

    float acc[32];
#pragma unroll
    for (int j = 0; j < 32; ++j) acc[j] = 0.0f;

    const int kw = wave * 32;                    // wave's k-offset within block
#pragma unroll
    for (int kk = 0; kk < 32; kk += 4) {
        const int k = k0 + kw + kk;
        float w[4];
#pragma unroll
        for (int i = 0; i < 4; ++i)
            w[i] = w1[(size_t)(k + i) * HID + lane];
#pragma unroll
        for (int bg = 0; bg < 4; ++bg) {
            float4 x[8];
#pragma unroll
            for (int j = 0; j < 8; ++j)
                x[j] = *(const float4*)(smem + (bg * 8 + j) * 128 + kw + kk);
#pragma unroll
            for (int i = 0; i < 4; ++i)
#pragma unroll
                for (int j = 0; j < 8; ++j)
                    acc[bg * 8 + j] = fmaf(((const float*)&x[j])[i], w[i],
                                           acc[bg * 8 + j]);
        }
    }
    __syncthreads();                             // all LDS reads done

    // --- Cross-wave reduce: wave w dumps accs into smem[w*2048 + ...] ---
#pragma unroll
    for (int j = 0; j < 32; ++j)
        smem[wave * 2048 + j * 64 + lane] = acc[j];
    __syncthreads();

#pragma unroll
    for (int t = 0; t < 8; ++t) {
        const int idx = tid + t * 256;           // 0..2047 = b*64+hid
        const float s = smem[idx] + smem[2048 + idx] +
                        smem[4096 + idx] + smem[6144 + idx];
        atomicAdd(hacc + idx, s);
    }
}

// ---------------- Kernel 2: h = tanh(acc + b1); theta = tanh(h @ w2 + b2) ----
__global__ __launch_bounds__(256) void k2_head(const float* __restrict__ hacc,
                                               const float* __restrict__ b1,
                                               const float* __restrict__ w2,
                                               const float* __restrict__ b2,
                                               float* __restrict__ theta) {
    __shared__ float h[BATCH * HID];
    const int tid = threadIdx.x;
    for (int idx = tid; idx < BATCH * HID; idx += 256)
        h[idx] = tanhf(hacc[idx] + b1[idx & (HID - 1)]);
    __syncthreads();
    if (tid < BATCH * 6) {
        const int b = tid / 6;
        const int j = tid - b * 6;
        float s = b2[j];
#pragma unroll
        for (int t = 0; t < HID; ++t)
            s = fmaf(h[b * HID + t], w2[t * 6 + j], s);
        theta[tid] = tanhf(s);
    }
}

// ---------------- Kernel 3: affine grid + bilinear sampling ------------------
__global__ __launch_bounds__(256) void k3_sample(const float* __restrict__ img,
                                                 const float* __restrict__ theta,
                                                 float* __restrict__ out) {
    const int b   = blockIdx.x / BLK3;
    const int pix = (blockIdx.x - b * BLK3) * 256 + threadIdx.x;
    const int i   = pix / WDIM;          // row (y)
    const int j   = pix - i * WDIM;      // col (x)

    const float* th = theta + b * 6;
    const float t0 = th[0], t1 = th[1], t2 = th[2];
    const float t3 = th[3], t4 = th[4], t5 = th[5];

    const float xt = (2.0f * (float)j - (float)(WDIM - 1)) / (float)(WDIM - 1);
    const float yt = (2.0f * (float)i - (float)(HDIM - 1)) / (float)(HDIM - 1);

    const float xs = t0 * xt + t1 * yt + t2;
    const float ys = t3 * xt + t4 * yt + t5;

    const float x = 0.5f * (xs + 1.0f) * (float)(WDIM - 1);
    const float y = 0.5f * (ys + 1.0f) * (float)(HDIM - 1);

    const int x0 = (int)floorf(x);
    const int y0 = (int)floorf(y);
    const int x1 = x0 + 1;
    const int y1 = y0 + 1;

    const int x0c = min(max(x0, 0), WDIM - 1);
    const int x1c = min(max(x1, 0), WDIM - 1);
    const int y0c = min(max(y0, 0), HDIM - 1);
    const int y1c = min(max(y1, 0), HDIM - 1);

    // Reference computes weights from the CLIPPED corner coordinates.
    const float x0f = (float)x0c, x1f = (float)x1c;
    const float y0f = (float)y0c, y1f = (float)y1c;

    const float wa = (x1f - x) * (y1f - y);
    const float wb = (x1f - x) * (y - y0f);
    const float wc = (x - x0f) * (y1f - y);
    const float wd = (x - x0f) * (y - y0f);

    const float* base = img + (size_t)b * KTOT;
    const float* pa = base + (size_t)(y0c * WDIM + x0c) * 3;
    const float* pb = base + (size_t)(y1c * WDIM + x0c) * 3;
    const float* pc = base + (size_t)(y0c * WDIM + x1c) * 3;
    const float* pd = base + (size_t)(y1c * WDIM + x1c) * 3;

    float* po = out + (size_t)b * KTOT + (size_t)pix * 3;
#pragma unroll
    for (int c = 0; c < 3; ++c)
        po[c] = wa * pa[c] + wb * pb[c] + wc * pc[c] + wd * pd[c];
}

extern "C" void kernel_launch(void* const* d_in, const int* in_sizes, int n_in,
                              void* d_out, int out_size, void* d_ws, size_t ws_size,
                              hipStream_t stream) {
    const float* inputs = (const float*)d_in[0];
    const float* w1     = (const float*)d_in[1];
    const float* b1     = (const float*)d_in[2];
    const float* w2     = (const float*)d_in[3];
    const float* b2     = (const float*)d_in[4];
    float* out = (float*)d_out;

    float* hacc  = (float*)d_ws;               // 32*64 floats
    float* theta = hacc + BATCH * HID;         // 32*6 floats

    hipMemsetAsync(hacc, 0, BATCH * HID * sizeof(float), stream);
    k1_gemm<<<NBLK1, 256, 0, stream>>>(inputs, w1, hacc);
    k2_head<<<1, 256, 0, stream>>>(hacc, b1, w2, b2, theta);
    k3_sample<<<BATCH * BLK3, 256, 0, stream>>>(inputs, theta, out);
}

// Round 3
// 141.373 us; speedup vs baseline: 1.1918x; 1.0044x over previous
//
#include <hip/hip_runtime.h>

#define BATCH 32
#define HDIM 224
#define WDIM 224
#define CDIM 3
#define KTOT (HDIM * WDIM * CDIM)   // 150528
#define HID 64
#define KCHUNK 128
#define NBLK1 (KTOT / KCHUNK)       // 1176
#define PIX (HDIM * WDIM)           // 50176
#define BLK3 49                      // blocks per batch: 256 thr * 4 px = 1024 px

// ---------------- Kernel 1: hacc = flat @ w1 (split-K, LDS-staged) ----------
// Block: 256 thr = 4 waves, owns k-range [k0, k0+128). Wave w owns 32 k's.
// Thread: lane = hid, accumulates all 32 batches. w1 slice prefetched to regs
// BEFORE the staging barrier -> exactly one latency exposure per block.
__global__ __launch_bounds__(256, 5) void k1_gemm(const float* __restrict__ flat,
                                                  const float* __restrict__ w1,
                                                  float* __restrict__ hacc) {
    __shared__ float smem[6144];                 // 24 KB dual-purpose
    const int tid  = threadIdx.x;
    const int lane = tid & 63;                   // hid
    const int wave = tid >> 6;
    const int k0   = blockIdx.x * KCHUNK;
    const int kw   = wave * 32;

    // --- Prefetch w1[k0+kw .. +32)[lane] into registers (32 indep loads) ---
    float w[32];
    const float* wp = w1 + (size_t)(k0 + kw) * HID + lane;
#pragma unroll
    for (int i = 0; i < 32; ++i)
        w[i] = wp[(size_t)i * HID];

    // --- Stage flat[32][k0..k0+128) into LDS (16 KB), coalesced float4 ---
#pragma unroll
    for (int t = 0; t < 4; ++t) {
        const int idx = tid + t * 256;           // 0..1023; smem addr = idx*4
        const int b   = idx >> 5;
        const int kq  = idx & 31;
        *(float4*)(smem + idx * 4) =
            *(const float4*)(flat + (size_t)b * KTOT + k0 + kq * 4);
    }
    __syncthreads();                             // drains w-prefetch too

    float acc[32];
#pragma unroll
    for (int j = 0; j < 32; ++j) acc[j] = 0.0f;

#pragma unroll
    for (int kk = 0; kk < 32; kk += 4) {
#pragma unroll
        for (int b = 0; b < 32; ++b) {
            const float4 x = *(const float4*)(smem + b * 128 + kw + kk);
            float a = acc[b];
            a = fmaf(x.x, w[kk + 0], a);
            a = fmaf(x.y, w[kk + 1], a);
            a = fmaf(x.z, w[kk + 2], a);
            a = fmaf(x.w, w[kk + 3], a);
            acc[b] = a;
        }
    }
    __syncthreads();                             // flat slice fully consumed

    // --- Waves 1..3 dump partials (24 KB); wave 0 reduces + atomics ---
    if (wave) {
#pragma unroll
        for (int j = 0; j < 32; ++j)
            smem[(wave - 1) * 2048 + j * 64 + lane] = acc[j];
    }
    __syncthreads();
    if (wave == 0) {
#pragma unroll
        for (int j = 0; j < 32; ++j) {
            const int idx = j * 64 + lane;
            atomicAdd(hacc + idx,
                      acc[j] + smem[idx] + smem[2048 + idx] + smem[4096 + idx]);
        }
    }
}

// -------- Kernel 3: head recompute + affine grid + bilinear sampling --------
__global__ __launch_bounds__(256) void k3_sample(const float* __restrict__ img,
                                                 const float* __restrict__ hacc,
                                                 const float* __restrict__ b1,
                                                 const float* __restrict__ w2,
                                                 const float* __restrict__ b2,
                                                 float* __restrict__ out) {
    const int b     = blockIdx.x / BLK3;
    const int strip = blockIdx.x - b * BLK3;
    const int tid   = threadIdx.x;

    __shared__ float sh[HID];
    __shared__ float sth[6];
    if (tid < HID)
        sh[tid] = tanhf(hacc[b * HID + tid] + b1[tid]);
    __syncthreads();
    if (tid < 6) {
        float s = b2[tid];
#pragma unroll
        for (int t = 0; t < HID; ++t)
            s = fmaf(sh[t], w2[t * 6 + tid], s);
        sth[tid] = tanhf(s);
    }
    __syncthreads();

    const float t0 = sth[0], t1 = sth[1], t2 = sth[2];
    const float t3 = sth[3], t4 = sth[4], t5 = sth[5];

    const float* base = img + (size_t)b * KTOT;
    const int pix0 = strip * 1024 + tid * 4;

    float res[12];
#pragma unroll
    for (int p = 0; p < 4; ++p) {
        const int pix = pix0 + p;
        const int i = pix / WDIM;
        const int j = pix - i * WDIM;

        const float xt = (2.0f * (float)j - (float)(WDIM - 1)) / (float)(WDIM - 1);
        const float yt = (2.0f * (float)i - (float)(HDIM - 1)) / (float)(HDIM - 1);

        const float xs = t0 * xt + t1 * yt + t2;
        const float ys = t3 * xt + t4 * yt + t5;

        const float x = 0.5f * (xs + 1.0f) * (float)(WDIM - 1);
        const float y = 0.5f * (ys + 1.0f) * (float)(HDIM - 1);

        const int x0 = (int)floorf(x);
        const int y0 = (int)floorf(y);

        const int x0c = min(max(x0, 0), WDIM - 1);
        const int x1c = min(max(x0 + 1, 0), WDIM - 1);
        const int y0c = min(max(y0, 0), HDIM - 1);
        const int y1c = min(max(y0 + 1, 0), HDIM - 1);

        // Reference computes weights from the CLIPPED corner coordinates.
        const float x0f = (float)x0c, x1f = (float)x1c;
        const float y0f = (float)y0c, y1f = (float)y1c;

        const float wa = (x1f - x) * (y1f - y);
        const float wb = (x1f - x) * (y - y0f);
        const float wc = (x - x0f) * (y1f - y);
        const float wd = (x - x0f) * (y - y0f);

        const float* pa = base + (size_t)(y0c * WDIM + x0c) * 3;
        const float* pb = base + (size_t)(y1c * WDIM + x0c) * 3;
        const float* pc = base + (size_t)(y0c * WDIM + x1c) * 3;
        const float* pd = base + (size_t)(y1c * WDIM + x1c) * 3;

#pragma unroll
        for (int c = 0; c < 3; ++c)
            res[p * 3 + c] = wa * pa[c] + wb * pb[c] + wc * pc[c] + wd * pd[c];
    }

    float4* po = (float4*)(out + (size_t)b * KTOT + (size_t)pix0 * 3);
    po[0] = make_float4(res[0], res[1], res[2],  res[3]);
    po[1] = make_float4(res[4], res[5], res[6],  res[7]);
    po[2] = make_float4(res[8], res[9], res[10], res[11]);
}

extern "C" void kernel_launch(void* const* d_in, const int* in_sizes, int n_in,
                              void* d_out, int out_size, void* d_ws, size_t ws_size,
                              hipStream_t stream) {
    const float* inputs = (const float*)d_in[0];
    const float* w1     = (const float*)d_in[1];
    const float* b1     = (const float*)d_in[2];
    const float* w2     = (const float*)d_in[3];
    const float* b2     = (const float*)d_in[4];
    float* out = (float*)d_out;

    float* hacc = (float*)d_ws;                  // 32*64 floats

    hipMemsetAsync(hacc, 0, BATCH * HID * sizeof(float), stream);
    k1_gemm<<<NBLK1, 256, 0, stream>>>(inputs, w1, hacc);
    k3_sample<<<BATCH * BLK3, 256, 0, stream>>>(inputs, hacc, b1, w2, b2, out);
}